// Round 10
// baseline (431.888 us; speedup 1.0000x reference)
//
#include <hip/hip_runtime.h>

// GCN 3-layer forward, fp32 — Round 10: XCD-sliced gather.
//   R9 finding: layer FETCH = 111 MB = 8 XCDs x 12.8 MB — every XCD's L2 pulls
//   the whole gather buffer. Fix: feature-slice the gather across XCDs.
//   Per layer:  S = agg(P)      (gather kernel; blockIdx%8 -> XCD -> 16-feat
//                                slice, per-XCD working set 3.2 MB, L2-resident)
//               out = S @ W     (gemm kernel; + bias, ReLU, x dinv prescale)
//   P buffers have a 64-float zero header; CSR lists padded to multiple of 4
//   with dummy src=-1 (col memset 0xFF) -> branchless unrolled gather, no tail.

#define FEAT 64
#define SCAN_B 1024
#define STILE 68   // s_tile stride: breaks 4-way LDS bank conflict on k-loop

typedef int v4i __attribute__((ext_vector_type(4)));

// ---------- CSR build ----------
// degree count; atomic return value = within-row rank of edge e.
__global__ void deg_rank_kernel(const int* __restrict__ dst, int* __restrict__ cnt,
                                int* __restrict__ rank, int E4) {
    int i = blockIdx.x * blockDim.x + threadIdx.x;
    if (i < E4) {
        v4i d = __builtin_nontemporal_load(((const v4i*)dst) + i);
        v4i r;
        r[0] = atomicAdd(&cnt[d[0]], 1);
        r[1] = atomicAdd(&cnt[d[1]], 1);
        r[2] = atomicAdd(&cnt[d[2]], 1);
        r[3] = atomicAdd(&cnt[d[3]], 1);
        __builtin_nontemporal_store(r, ((v4i*)rank) + i);
    }
}

// Pass 1: exclusive scan over PADDED counts ((cnt+3)&~3) -> rowptr, bsum.
// dinv from RAW count: rsqrt(1+cnt).
__global__ __launch_bounds__(SCAN_B) void scan_partial_kernel(
    const int* __restrict__ cnt, int* __restrict__ rowptr,
    int* __restrict__ bsum, float* __restrict__ dinv, int n) {
    __shared__ int wsum[SCAN_B / 64 + 1];
    const int tid  = threadIdx.x;
    const int lane = tid & 63;
    const int wid  = tid >> 6;
    const int i = blockIdx.x * SCAN_B + tid;

    int vr = (i < n) ? cnt[i] : 0;
    if (i < n) dinv[i] = rsqrtf((float)(1 + vr));
    int v = (vr + 3) & ~3;            // pad each list to multiple of 4
    int incl = v;
#pragma unroll
    for (int off = 1; off < 64; off <<= 1) {
        int t = __shfl_up(incl, off, 64);
        if (lane >= off) incl += t;
    }
    if (lane == 63) wsum[wid] = incl;
    __syncthreads();
    if (tid == 0) {
        int run = 0;
#pragma unroll
        for (int w = 0; w < SCAN_B / 64; ++w) { int t = wsum[w]; wsum[w] = run; run += t; }
        wsum[SCAN_B / 64] = run;
        bsum[blockIdx.x] = run;
    }
    __syncthreads();
    if (i < n) rowptr[i] = incl - v + wsum[wid];
}

// Pass 2: exclusive scan of block sums, single block, nb <= 1024.
__global__ __launch_bounds__(SCAN_B) void scan_sums_kernel(int* __restrict__ bsum, int nb) {
    __shared__ int wsum[SCAN_B / 64 + 1];
    const int tid  = threadIdx.x;
    const int lane = tid & 63;
    const int wid  = tid >> 6;
    int v = (tid < nb) ? bsum[tid] : 0;
    int incl = v;
#pragma unroll
    for (int off = 1; off < 64; off <<= 1) {
        int t = __shfl_up(incl, off, 64);
        if (lane >= off) incl += t;
    }
    if (lane == 63) wsum[wid] = incl;
    __syncthreads();
    if (tid == 0) {
        int run = 0;
#pragma unroll
        for (int w = 0; w < SCAN_B / 64; ++w) { int t = wsum[w]; wsum[w] = run; run += t; }
        wsum[SCAN_B / 64] = run;
    }
    __syncthreads();
    if (tid < nb) bsum[tid] = incl - v + wsum[wid];
    if (tid == 0) bsum[nb] = wsum[SCAN_B / 64];
}

// Pass 3: add block offsets; write rowptr[n].
__global__ __launch_bounds__(SCAN_B) void scan_add_kernel(
    int* __restrict__ rowptr, const int* __restrict__ bsum, int n, int nb) {
    const int i = blockIdx.x * SCAN_B + (int)threadIdx.x;
    if (i < n) rowptr[i] += bsum[blockIdx.x];
    if (i == 0) rowptr[n] = bsum[nb];
}

// Atomic-free CSR fill. Padding slots keep their memset value (-1 = dummy).
__global__ void fill_kernel(const int* __restrict__ src, const int* __restrict__ dst,
                            const int* __restrict__ rank, const int* __restrict__ rowptr,
                            int* __restrict__ col, int E4) {
    int i = blockIdx.x * blockDim.x + threadIdx.x;
    if (i < E4) {
        v4i s = __builtin_nontemporal_load(((const v4i*)src) + i);
        v4i d = __builtin_nontemporal_load(((const v4i*)dst) + i);
        v4i r = __builtin_nontemporal_load(((const v4i*)rank) + i);
        col[rowptr[d[0]] + r[0]] = s[0];
        col[rowptr[d[1]] + r[1]] = s[1];
        col[rowptr[d[2]] + r[2]] = s[2];
        col[rowptr[d[3]] + r[3]] = s[3];
    }
}

// Pz[i] = x[i] * dinv[row]   (i indexes float4s; 16 per row; Pz = P + 64 header)
__global__ void prescale_kernel(const float* __restrict__ x, const float* __restrict__ dinv,
                                float* __restrict__ pz, int nq) {
    int i = blockIdx.x * blockDim.x + threadIdx.x;
    if (i < nq) {
        float d = dinv[i >> 4];
        float4 v = ((const float4*)x)[i];
        ((float4*)pz)[i] = make_float4(v.x * d, v.y * d, v.z * d, v.w * d);
    }
}

// ---------- gather: S[g][slice*16..+16] = Pz[g] + sum_{s in list(g)} Pz[s] ----
// blockIdx%8 = q: slice = q>>1 (XCD pair shares a 16-feat slice = 3.2 MB,
// L2-resident per XCD), parity q&1 splits node groups between the pair.
// 16 nodes x 16 lanes; 1 scalar float per lane per edge; 4-unrolled, padded
// lists (dummy s=-1 hits the zero header) -> no remainder, no divergence.
__global__ __launch_bounds__(256) void gather_kernel(
    const int* __restrict__ rowptr, const int* __restrict__ col,
    const float* __restrict__ Pz, float* __restrict__ S, int n) {
    const int q      = blockIdx.x & 7;
    const int sg     = blockIdx.x >> 3;
    const int group  = sg * 2 + (q & 1);
    const int slice  = q >> 1;
    const int t  = threadIdx.x;
    const int r  = t >> 4;
    const int c4 = t & 15;
    const int g  = group * 16 + r;
    if (g >= n) return;
    const int sf = slice * 16 + c4;
    const float* __restrict__ P = Pz + sf;   // row s -> P[s*64]; s=-1 -> header

    float a0 = P[g * 64];   // self-loop (input pre-scaled)
    float a1 = 0.f, a2 = 0.f, a3 = 0.f;
    int p = rowptr[g];
    const int end = rowptr[g + 1];
    for (; p < end; p += 4) {
        const int s0 = col[p + 0];
        const int s1 = col[p + 1];
        const int s2 = col[p + 2];
        const int s3 = col[p + 3];
        a0 += P[s0 * 64];
        a1 += P[s1 * 64];
        a2 += P[s2 * 64];
        a3 += P[s3 * 64];
    }
    S[g * 64 + sf] = (a0 + a1) + (a2 + a3);
}

// ---------- GEMM + epilogue: out = S @ W, o = acc*dinv + b (+ReLU, +prescale)
template<int INTER>
__global__ __launch_bounds__(256) void gemm_kernel(
    const float* __restrict__ S, const float* __restrict__ W,
    const float* __restrict__ bias, const float* __restrict__ dinv,
    float* __restrict__ outz, int n) {
    __shared__ float w_lds[FEAT * FEAT];   // [k][c]
    __shared__ float s_tile[16 * STILE];   // [r][k], padded

    const int t = threadIdx.x;
#pragma unroll
    for (int i = 0; i < 4; ++i) {
        int idx = (i * 256 + t) * 4;
        *(float4*)&w_lds[idx] = *(const float4*)&W[idx];
    }

    const int r  = t >> 4;
    const int c4 = t & 15;
    const int g  = blockIdx.x * 16 + r;
    if (g >= n) { __syncthreads(); return; }
    const int f = c4 * 4;

    *(float4*)&s_tile[r * STILE + f] = *(const float4*)&S[g * 64 + f];
    __syncthreads();   // covers w_lds; s_tile rows are wave-private anyway

    float4 acc = make_float4(0.f, 0.f, 0.f, 0.f);
#pragma unroll
    for (int k = 0; k < FEAT; ++k) {
        const float sv = s_tile[r * STILE + k];
        const float4 wv = *(const float4*)&w_lds[k * FEAT + f];
        acc.x += sv * wv.x; acc.y += sv * wv.y;
        acc.z += sv * wv.z; acc.w += sv * wv.w;
    }

    const float dg = dinv[g];
    const float4 bv = *(const float4*)&bias[f];
    float4 o = make_float4(acc.x * dg + bv.x, acc.y * dg + bv.y,
                           acc.z * dg + bv.z, acc.w * dg + bv.w);
    if (INTER) {   // ReLU, then pre-scale for the next layer's gather
        o.x = fmaxf(o.x, 0.f) * dg; o.y = fmaxf(o.y, 0.f) * dg;
        o.z = fmaxf(o.z, 0.f) * dg; o.w = fmaxf(o.w, 0.f) * dg;
    }
    *(float4*)&outz[(size_t)g * 64 + f] = o;
}

extern "C" void kernel_launch(void* const* d_in, const int* in_sizes, int n_in,
                              void* d_out, int out_size, void* d_ws, size_t ws_size,
                              hipStream_t stream) {
    const float* x  = (const float*)d_in[0];
    const int*   ei = (const int*)d_in[1];
    const float* W0 = (const float*)d_in[2];
    const float* b0 = (const float*)d_in[3];
    const float* W1 = (const float*)d_in[4];
    const float* b1 = (const float*)d_in[5];
    const float* W2 = (const float*)d_in[6];
    const float* b2 = (const float*)d_in[7];
    float* out = (float*)d_out;

    const int N = in_sizes[0] / FEAT;   // 50000 (divisible by 16)
    const int E = in_sizes[1] / 2;      // 800000 (divisible by 4)
    const int* src = ei;
    const int* dst = ei + E;

    const int nbScan = (N + SCAN_B - 1) / SCAN_B;   // 49
    const int Ecap = E + 4 * N;                      // padded col capacity

    // workspace layout
    char* w = (char*)d_ws;
    int*   cnt    = (int*)w;                 w += sizeof(int) * (size_t)N;
    int*   rowptr = (int*)w;                 w += sizeof(int) * (size_t)(N + 1);
    int*   bsum   = (int*)w;                 w += sizeof(int) * (size_t)(nbScan + 1);
    int*   col    = (int*)w;                 w += sizeof(int) * (size_t)Ecap;
    float* dinv   = (float*)w;               w += sizeof(float) * (size_t)N;
    float* P1     = (float*)w;               w += sizeof(float) * (64 + (size_t)N * FEAT);
    float* P2     = (float*)w;               w += sizeof(float) * (64 + (size_t)N * FEAT);
    float* S      = (float*)w;               w += sizeof(float) * ((size_t)N * FEAT);
    int*   rank   = (int*)S;    // alias: rank dead before gather writes S
    float* P1z = P1 + 64;       // headers stay zero: dummy src=-1 lands there
    float* P2z = P2 + 64;

    const int tB = 256;
    const int E4  = E / 4;
    const int gE4 = (E4 + tB - 1) / tB;
    const int g16 = (N + 15) / 16;                    // 3125
    const int gGa = ((g16 + 1) / 2) * 8;              // gather grid (XCD-sliced)
    const int nq  = N * FEAT / 4;
    const int gQ  = (nq + tB - 1) / tB;

    // CSR build (shared by all 3 layers)
    hipMemsetAsync(cnt, 0, sizeof(int) * (size_t)N, stream);
    hipMemsetAsync(col, 0xFF, sizeof(int) * (size_t)Ecap, stream);  // dummy = -1
    deg_rank_kernel<<<gE4, tB, 0, stream>>>(dst, cnt, rank, E4);
    scan_partial_kernel<<<nbScan, SCAN_B, 0, stream>>>(cnt, rowptr, bsum, dinv, N);
    scan_sums_kernel<<<1, SCAN_B, 0, stream>>>(bsum, nbScan);
    scan_add_kernel<<<nbScan, SCAN_B, 0, stream>>>(rowptr, bsum, N, nbScan);
    fill_kernel<<<gE4, tB, 0, stream>>>(src, dst, rank, rowptr, col, E4);

    // zero headers + prescale input
    hipMemsetAsync(P1, 0, 64 * sizeof(float), stream);
    hipMemsetAsync(P2, 0, 64 * sizeof(float), stream);
    prescale_kernel<<<gQ, tB, 0, stream>>>(x, dinv, P1z, nq);

    // layer 0
    gather_kernel<<<gGa, tB, 0, stream>>>(rowptr, col, P1z, S, N);
    gemm_kernel<1><<<g16, tB, 0, stream>>>(S, W0, b0, dinv, P2z, N);
    // layer 1
    gather_kernel<<<gGa, tB, 0, stream>>>(rowptr, col, P2z, S, N);
    gemm_kernel<1><<<g16, tB, 0, stream>>>(S, W1, b1, dinv, P1z, N);
    // layer 2
    gather_kernel<<<gGa, tB, 0, stream>>>(rowptr, col, P1z, S, N);
    gemm_kernel<0><<<g16, tB, 0, stream>>>(S, W2, b2, dinv, out, N);
}

// Round 11
// 238.576 us; speedup vs baseline: 1.8103x; 1.8103x over previous
//
#include <hip/hip_runtime.h>

// GCN 3-layer forward, fp32 — Round 11: R7 layer structure + rebuilt fill path.
//   Layers (proven): gather-sum (node-parallel, float4, 8-wide branch-free over
//   padded lists) -> in-block LDS GEMM -> bias/ReLU/prescale epilogue.
//   Fill path: pos precompute (streaming) + dst-range-partitioned scatter
//   (blockIdx&7 -> XCD owns a contiguous col region -> no partial-line
//   writebacks crossing XCDs; WRITE_SIZE 52 MB -> ~5 MB).
//   CSR lists padded to multiple of 8 with dummy src = N; P buffers carry a
//   zeroed row N so dummy gathers add 0. Prescale pass writes P1 = x*dinv.

#define FEAT 64
#define SCAN_B 1024
#define STILE 68   // s_tile stride: breaks 4-way LDS bank conflict on k-loop

typedef int v4i __attribute__((ext_vector_type(4)));

// ---------- CSR build ----------
// degree count; atomic return value = within-row rank of edge e.
__global__ void deg_rank_kernel(const int* __restrict__ dst, int* __restrict__ cnt,
                                int* __restrict__ rank, int E4) {
    int i = blockIdx.x * blockDim.x + threadIdx.x;
    if (i < E4) {
        v4i d = __builtin_nontemporal_load(((const v4i*)dst) + i);
        v4i r;
        r[0] = atomicAdd(&cnt[d[0]], 1);
        r[1] = atomicAdd(&cnt[d[1]], 1);
        r[2] = atomicAdd(&cnt[d[2]], 1);
        r[3] = atomicAdd(&cnt[d[3]], 1);
        __builtin_nontemporal_store(r, ((v4i*)rank) + i);
    }
}

// Pass 1: exclusive scan over counts PADDED to multiple of 8 -> rowptr, bsum.
// dinv from RAW count: rsqrt(1+cnt).
__global__ __launch_bounds__(SCAN_B) void scan_partial_kernel(
    const int* __restrict__ cnt, int* __restrict__ rowptr,
    int* __restrict__ bsum, float* __restrict__ dinv, int n) {
    __shared__ int wsum[SCAN_B / 64 + 1];
    const int tid  = threadIdx.x;
    const int lane = tid & 63;
    const int wid  = tid >> 6;
    const int i = blockIdx.x * SCAN_B + tid;

    int vr = (i < n) ? cnt[i] : 0;
    if (i < n) dinv[i] = rsqrtf((float)(1 + vr));
    int v = (vr + 7) & ~7;            // pad each list to multiple of 8
    int incl = v;
#pragma unroll
    for (int off = 1; off < 64; off <<= 1) {
        int t = __shfl_up(incl, off, 64);
        if (lane >= off) incl += t;
    }
    if (lane == 63) wsum[wid] = incl;
    __syncthreads();
    if (tid == 0) {
        int run = 0;
#pragma unroll
        for (int w = 0; w < SCAN_B / 64; ++w) { int t = wsum[w]; wsum[w] = run; run += t; }
        wsum[SCAN_B / 64] = run;
        bsum[blockIdx.x] = run;
    }
    __syncthreads();
    if (i < n) rowptr[i] = incl - v + wsum[wid];
}

// Pass 2: exclusive scan of block sums, single block, nb <= 1024.
__global__ __launch_bounds__(SCAN_B) void scan_sums_kernel(int* __restrict__ bsum, int nb) {
    __shared__ int wsum[SCAN_B / 64 + 1];
    const int tid  = threadIdx.x;
    const int lane = tid & 63;
    const int wid  = tid >> 6;
    int v = (tid < nb) ? bsum[tid] : 0;
    int incl = v;
#pragma unroll
    for (int off = 1; off < 64; off <<= 1) {
        int t = __shfl_up(incl, off, 64);
        if (lane >= off) incl += t;
    }
    if (lane == 63) wsum[wid] = incl;
    __syncthreads();
    if (tid == 0) {
        int run = 0;
#pragma unroll
        for (int w = 0; w < SCAN_B / 64; ++w) { int t = wsum[w]; wsum[w] = run; run += t; }
        wsum[SCAN_B / 64] = run;
    }
    __syncthreads();
    if (tid < nb) bsum[tid] = incl - v + wsum[wid];
    if (tid == 0) bsum[nb] = wsum[SCAN_B / 64];
}

// Pass 3: add block offsets; write rowptr[n].
__global__ __launch_bounds__(SCAN_B) void scan_add_kernel(
    int* __restrict__ rowptr, const int* __restrict__ bsum, int n, int nb) {
    const int i = blockIdx.x * SCAN_B + (int)threadIdx.x;
    if (i < n) rowptr[i] += bsum[blockIdx.x];
    if (i == 0) rowptr[n] = bsum[nb];
}

// pos[e] = rowptr[dst[e]] + rank[e]   (pure streaming except rowptr gather,
// which hits a 200 KB L2-resident table)
__global__ void pos_kernel(const int* __restrict__ dst, const int* __restrict__ rank,
                           const int* __restrict__ rowptr, int* __restrict__ pos, int E4) {
    int i = blockIdx.x * blockDim.x + threadIdx.x;
    if (i < E4) {
        v4i d = __builtin_nontemporal_load(((const v4i*)dst) + i);
        v4i r = __builtin_nontemporal_load(((const v4i*)rank) + i);
        v4i p;
        p[0] = rowptr[d[0]] + r[0];
        p[1] = rowptr[d[1]] + r[1];
        p[2] = rowptr[d[2]] + r[2];
        p[3] = rowptr[d[3]] + r[3];
        __builtin_nontemporal_store(p, ((v4i*)pos) + i);
    }
}

// Write dummy entries into each list's padding slots (near-sequential writes).
__global__ void pad_kernel(const int* __restrict__ cnt, const int* __restrict__ rowptr,
                           int* __restrict__ col, int n, int dummy) {
    int g = blockIdx.x * blockDim.x + threadIdx.x;
    if (g < n) {
        int s = rowptr[g] + cnt[g];
        int e = rowptr[g + 1];
        for (int p = s; p < e; ++p) col[p] = dummy;
    }
}

// dst-range-partitioned scatter: q = blockIdx&7 owns nodes [q*qn,(q+1)*qn) ->
// contiguous col positions [rowptr[lo], rowptr[hi]). Only q writes those lines.
__global__ void scatter_kernel(const int* __restrict__ pos, const int* __restrict__ src,
                               const int* __restrict__ rowptr, int* __restrict__ col,
                               int E4, int qn, int n) {
    const int q = blockIdx.x & 7;
    const int i = (blockIdx.x >> 3) * blockDim.x + threadIdx.x;
    const int nlo = q * qn;
    const int nhi = (nlo + qn < n) ? nlo + qn : n;
    const int lo = rowptr[nlo];
    const int hi = rowptr[nhi];
    if (i < E4) {
        v4i p = __builtin_nontemporal_load(((const v4i*)pos) + i);
        v4i s = __builtin_nontemporal_load(((const v4i*)src) + i);
        if (p[0] >= lo && p[0] < hi) col[p[0]] = s[0];
        if (p[1] >= lo && p[1] < hi) col[p[1]] = s[1];
        if (p[2] >= lo && p[2] < hi) col[p[2]] = s[2];
        if (p[3] >= lo && p[3] < hi) col[p[3]] = s[3];
    }
}

// P[i] = x[i] * dinv[row]   (i indexes float4s; 16 per row)
__global__ void prescale_kernel(const float* __restrict__ x, const float* __restrict__ dinv,
                                float* __restrict__ pz, int nq) {
    int i = blockIdx.x * blockDim.x + threadIdx.x;
    if (i < nq) {
        float d = dinv[i >> 4];
        float4 v = ((const float4*)x)[i];
        ((float4*)pz)[i] = make_float4(v.x * d, v.y * d, v.z * d, v.w * d);
    }
}

// ---------- fused layer: gather-sum -> LDS -> GEMM -> bias/act ----------
// 16 nodes/block, 16 lanes/node (float4/lane). Lists are padded to x8 and
// terminated by construction: branch-free 8-wide loop, col read as 2x int4,
// 8 float4 gathers in flight, 4 independent accumulators. Dummy entries point
// at the zeroed row N of the P buffer. Input is pre-scaled by dinv[src].
template<int INTER>
__global__ __launch_bounds__(256) void layer_kernel(
    const int* __restrict__ rowptr, const int* __restrict__ col,
    const float* __restrict__ dinv, const float* __restrict__ Xs,
    const float* __restrict__ W, const float* __restrict__ bias,
    float* __restrict__ out, int n) {
    __shared__ float w_lds[FEAT * FEAT];   // [k][c]
    __shared__ float s_tile[16 * STILE];   // [r][k], padded

    const int t = threadIdx.x;
#pragma unroll
    for (int i = 0; i < 4; ++i) {
        int idx = (i * 256 + t) * 4;
        *(float4*)&w_lds[idx] = *(const float4*)&W[idx];
    }
    __syncthreads();   // W visible; nothing else needs a barrier below

    const int r  = t >> 4;       // local node 0..15
    const int c4 = t & 15;       // float4 feature group
    const int g  = blockIdx.x * 16 + r;
    if (g >= n) return;
    const int f = c4 * 4;
    const float* __restrict__ Hf = Xs + f;

    // self-loop term (input pre-scaled)
    float4 a0 = *(const float4*)&Hf[(size_t)g * FEAT];
    float4 a1 = make_float4(0.f, 0.f, 0.f, 0.f);
    float4 a2 = make_float4(0.f, 0.f, 0.f, 0.f);
    float4 a3 = make_float4(0.f, 0.f, 0.f, 0.f);

    int p = rowptr[g];
    const int end = rowptr[g + 1];   // end - p is a multiple of 8

    for (; p < end; p += 8) {
        const v4i c0 = *(const v4i*)&col[p];
        const v4i c1 = *(const v4i*)&col[p + 4];
        const float4 h0 = *(const float4*)&Hf[(size_t)c0[0] * FEAT];
        const float4 h1 = *(const float4*)&Hf[(size_t)c0[1] * FEAT];
        const float4 h2 = *(const float4*)&Hf[(size_t)c0[2] * FEAT];
        const float4 h3 = *(const float4*)&Hf[(size_t)c0[3] * FEAT];
        const float4 h4 = *(const float4*)&Hf[(size_t)c1[0] * FEAT];
        const float4 h5 = *(const float4*)&Hf[(size_t)c1[1] * FEAT];
        const float4 h6 = *(const float4*)&Hf[(size_t)c1[2] * FEAT];
        const float4 h7 = *(const float4*)&Hf[(size_t)c1[3] * FEAT];
        a0.x += h0.x; a0.y += h0.y; a0.z += h0.z; a0.w += h0.w;
        a1.x += h1.x; a1.y += h1.y; a1.z += h1.z; a1.w += h1.w;
        a2.x += h2.x; a2.y += h2.y; a2.z += h2.z; a2.w += h2.w;
        a3.x += h3.x; a3.y += h3.y; a3.z += h3.z; a3.w += h3.w;
        a0.x += h4.x; a0.y += h4.y; a0.z += h4.z; a0.w += h4.w;
        a1.x += h5.x; a1.y += h5.y; a1.z += h5.z; a1.w += h5.w;
        a2.x += h6.x; a2.y += h6.y; a2.z += h6.z; a2.w += h6.w;
        a3.x += h7.x; a3.y += h7.y; a3.z += h7.z; a3.w += h7.w;
    }
    float4 S = make_float4((a0.x + a1.x) + (a2.x + a3.x),
                           (a0.y + a1.y) + (a2.y + a3.y),
                           (a0.z + a1.z) + (a2.z + a3.z),
                           (a0.w + a1.w) + (a2.w + a3.w));
    *(float4*)&s_tile[r * STILE + f] = S;
    // no __syncthreads: wave w reads only rows 4w..4w+3, which it wrote

    // in-block GEMM: T[r][f..f+3] = sum_k S[r][k] * W[k][f..f+3]
    float4 acc = make_float4(0.f, 0.f, 0.f, 0.f);
#pragma unroll
    for (int k = 0; k < FEAT; ++k) {
        const float sv = s_tile[r * STILE + k];
        const float4 wv = *(const float4*)&w_lds[k * FEAT + f];
        acc.x += sv * wv.x; acc.y += sv * wv.y;
        acc.z += sv * wv.z; acc.w += sv * wv.w;
    }

    const float dg = dinv[g];
    const float4 bv = *(const float4*)&bias[f];
    float4 o = make_float4(acc.x * dg + bv.x, acc.y * dg + bv.y,
                           acc.z * dg + bv.z, acc.w * dg + bv.w);
    if (INTER) {   // ReLU, then pre-scale for next layer's gather
        o.x = fmaxf(o.x, 0.f) * dg; o.y = fmaxf(o.y, 0.f) * dg;
        o.z = fmaxf(o.z, 0.f) * dg; o.w = fmaxf(o.w, 0.f) * dg;
    }
    *(float4*)&out[(size_t)g * FEAT + f] = o;
}

extern "C" void kernel_launch(void* const* d_in, const int* in_sizes, int n_in,
                              void* d_out, int out_size, void* d_ws, size_t ws_size,
                              hipStream_t stream) {
    const float* x  = (const float*)d_in[0];
    const int*   ei = (const int*)d_in[1];
    const float* W0 = (const float*)d_in[2];
    const float* b0 = (const float*)d_in[3];
    const float* W1 = (const float*)d_in[4];
    const float* b1 = (const float*)d_in[5];
    const float* W2 = (const float*)d_in[6];
    const float* b2 = (const float*)d_in[7];
    float* out = (float*)d_out;

    const int N = in_sizes[0] / FEAT;   // 50000
    const int E = in_sizes[1] / 2;      // 800000 (divisible by 4)
    const int* src = ei;
    const int* dst = ei + E;

    const int nbScan = (N + SCAN_B - 1) / SCAN_B;   // 49
    const int Ecap = E + 8 * N;                      // padded col capacity

    // workspace layout (64B-aligned regions)
    char* w = (char*)d_ws;
    auto take = [&](size_t bytes) { char* p = w; w += (bytes + 63) & ~(size_t)63; return p; };
    int*   cnt    = (int*)take(sizeof(int) * (size_t)N);
    int*   rowptr = (int*)take(sizeof(int) * (size_t)(N + 1));
    int*   bsum   = (int*)take(sizeof(int) * (size_t)(nbScan + 1));
    int*   col    = (int*)take(sizeof(int) * (size_t)Ecap);
    float* dinv   = (float*)take(sizeof(float) * (size_t)N);
    float* P1     = (float*)take(sizeof(float) * ((size_t)(N + 1) * FEAT));
    float* P2     = (float*)take(sizeof(float) * ((size_t)(N + 1) * FEAT));
    int*   rank = (int*)P2;   // alias: dead before layer-0 gemm writes P2
    int*   pos  = (int*)P1;   // alias: dead before prescale writes P1

    const int tB = 256;
    const int gN  = (N + tB - 1) / tB;
    const int E4  = E / 4;
    const int gE4 = (E4 + tB - 1) / tB;
    const int g16 = (N + 15) / 16;
    const int qn  = (N + 7) / 8;        // nodes per scatter partition
    const int nq  = N * FEAT / 4;
    const int gQ  = (nq + tB - 1) / tB;

    // CSR build (shared by all 3 layers)
    hipMemsetAsync(cnt, 0, sizeof(int) * (size_t)N, stream);
    deg_rank_kernel<<<gE4, tB, 0, stream>>>(dst, cnt, rank, E4);
    scan_partial_kernel<<<nbScan, SCAN_B, 0, stream>>>(cnt, rowptr, bsum, dinv, N);
    scan_sums_kernel<<<1, SCAN_B, 0, stream>>>(bsum, nbScan);
    scan_add_kernel<<<nbScan, SCAN_B, 0, stream>>>(rowptr, bsum, N, nbScan);
    pos_kernel<<<gE4, tB, 0, stream>>>(dst, rank, rowptr, pos, E4);
    pad_kernel<<<gN, tB, 0, stream>>>(cnt, rowptr, col, N, N);
    scatter_kernel<<<gE4 * 8, tB, 0, stream>>>(pos, src, rowptr, col, E4, qn, N);

    // prescale input into P1 (after scatter consumed pos); zero row N of P1/P2
    prescale_kernel<<<gQ, tB, 0, stream>>>(x, dinv, P1, nq);
    hipMemsetAsync(P1 + (size_t)N * FEAT, 0, FEAT * sizeof(float), stream);
    hipMemsetAsync(P2 + (size_t)N * FEAT, 0, FEAT * sizeof(float), stream);

    // fused layers
    layer_kernel<1><<<g16, tB, 0, stream>>>(rowptr, col, dinv, P1, W0, b0, P2, N);
    layer_kernel<1><<<g16, tB, 0, stream>>>(rowptr, col, dinv, P2, W1, b1, P1, N);
    layer_kernel<0><<<g16, tB, 0, stream>>>(rowptr, col, dinv, P1, W2, b2, out, N);
}

// Round 12
// 234.724 us; speedup vs baseline: 1.8400x; 1.0164x over previous
//
#include <hip/hip_runtime.h>

// GCN 3-layer forward, fp32 — Round 12: build-path consolidation.
//   Layers (proven, R11): gather-sum (node-parallel float4, 8-wide branch-free
//   over x8-padded lists, dummy=N -> zeroed row N) -> LDS GEMM -> epilogue.
//   Build: deg_rank -> scan_partial -> scan_finish (fused bsum-scan + offset
//   add + list padding) -> pos -> scatter (8x dst-range partitioned) ->
//   prescale (fused P1/P2 row-N zeroing). 10 dispatches total.

#define FEAT 64
#define SCAN_B 1024
#define STILE 68   // s_tile stride: breaks 4-way LDS bank conflict on k-loop

typedef int v4i __attribute__((ext_vector_type(4)));

// ---------- CSR build ----------
// degree count; atomic return value = within-row rank of edge e.
__global__ void deg_rank_kernel(const int* __restrict__ dst, int* __restrict__ cnt,
                                int* __restrict__ rank, int E4) {
    int i = blockIdx.x * blockDim.x + threadIdx.x;
    if (i < E4) {
        v4i d = __builtin_nontemporal_load(((const v4i*)dst) + i);
        v4i r;
        r[0] = atomicAdd(&cnt[d[0]], 1);
        r[1] = atomicAdd(&cnt[d[1]], 1);
        r[2] = atomicAdd(&cnt[d[2]], 1);
        r[3] = atomicAdd(&cnt[d[3]], 1);
        __builtin_nontemporal_store(r, ((v4i*)rank) + i);
    }
}

// Pass 1: exclusive scan over counts PADDED to multiple of 8 -> rowptr
// (chunk-local), bsum. dinv from RAW count: rsqrt(1+cnt).
__global__ __launch_bounds__(SCAN_B) void scan_partial_kernel(
    const int* __restrict__ cnt, int* __restrict__ rowptr,
    int* __restrict__ bsum, float* __restrict__ dinv, int n) {
    __shared__ int wsum[SCAN_B / 64 + 1];
    const int tid  = threadIdx.x;
    const int lane = tid & 63;
    const int wid  = tid >> 6;
    const int i = blockIdx.x * SCAN_B + tid;

    int vr = (i < n) ? cnt[i] : 0;
    if (i < n) dinv[i] = rsqrtf((float)(1 + vr));
    int v = (vr + 7) & ~7;            // pad each list to multiple of 8
    int incl = v;
#pragma unroll
    for (int off = 1; off < 64; off <<= 1) {
        int t = __shfl_up(incl, off, 64);
        if (lane >= off) incl += t;
    }
    if (lane == 63) wsum[wid] = incl;
    __syncthreads();
    if (tid == 0) {
        int run = 0;
#pragma unroll
        for (int w = 0; w < SCAN_B / 64; ++w) { int t = wsum[w]; wsum[w] = run; run += t; }
        wsum[SCAN_B / 64] = run;
        bsum[blockIdx.x] = run;
    }
    __syncthreads();
    if (i < n) rowptr[i] = incl - v + wsum[wid];
}

// Pass 2 (fused): every block wave-scans bsum (nb<=64) to get its own offset,
// adds it, writes rowptr[n], and fills each list's padding slots with dummy.
__global__ __launch_bounds__(SCAN_B) void scan_finish_kernel(
    const int* __restrict__ cnt, int* __restrict__ rowptr,
    const int* __restrict__ bsum, int* __restrict__ col,
    int n, int nb, int dummy) {
    __shared__ int s_off, s_tot;
    const int tid = threadIdx.x;
    if (tid < 64) {
        int v = (tid < nb) ? bsum[tid] : 0;
        int incl = v;
#pragma unroll
        for (int off = 1; off < 64; off <<= 1) {
            int t = __shfl_up(incl, off, 64);
            if ((tid & 63) >= off) incl += t;
        }
        if (tid == (int)blockIdx.x) s_off = incl - v;  // exclusive offset
        if (tid == 63) s_tot = incl;                   // grand total
    }
    __syncthreads();
    const int i = blockIdx.x * SCAN_B + tid;
    if (i < n) {
        const int rp = rowptr[i] + s_off;
        rowptr[i] = rp;
        const int c = cnt[i];
        const int e = rp + ((c + 7) & ~7);
        for (int p = rp + c; p < e; ++p) col[p] = dummy;
    }
    if (i == 0) rowptr[n] = s_tot;
}

// pos[e] = rowptr[dst[e]] + rank[e]   (streaming; rowptr table is L2-resident)
__global__ void pos_kernel(const int* __restrict__ dst, const int* __restrict__ rank,
                           const int* __restrict__ rowptr, int* __restrict__ pos, int E4) {
    int i = blockIdx.x * blockDim.x + threadIdx.x;
    if (i < E4) {
        v4i d = __builtin_nontemporal_load(((const v4i*)dst) + i);
        v4i r = __builtin_nontemporal_load(((const v4i*)rank) + i);
        v4i p;
        p[0] = rowptr[d[0]] + r[0];
        p[1] = rowptr[d[1]] + r[1];
        p[2] = rowptr[d[2]] + r[2];
        p[3] = rowptr[d[3]] + r[3];
        __builtin_nontemporal_store(p, ((v4i*)pos) + i);
    }
}

// dst-range-partitioned scatter: q = blockIdx&7 owns col range
// [rowptr[q*qn], rowptr[min((q+1)*qn,n)]). One XCD per partition -> full-line
// writebacks, no cross-XCD partial lines.
__global__ void scatter_kernel(const int* __restrict__ pos, const int* __restrict__ src,
                               const int* __restrict__ rowptr, int* __restrict__ col,
                               int E4, int qn, int n) {
    const int q = blockIdx.x & 7;
    const int i = (blockIdx.x >> 3) * blockDim.x + threadIdx.x;
    const int nlo = q * qn;
    const int nhi = (nlo + qn < n) ? nlo + qn : n;
    const int lo = rowptr[nlo];
    const int hi = rowptr[nhi];
    if (i < E4) {
        v4i p = __builtin_nontemporal_load(((const v4i*)pos) + i);
        v4i s = __builtin_nontemporal_load(((const v4i*)src) + i);
        if (p[0] >= lo && p[0] < hi) col[p[0]] = s[0];
        if (p[1] >= lo && p[1] < hi) col[p[1]] = s[1];
        if (p[2] >= lo && p[2] < hi) col[p[2]] = s[2];
        if (p[3] >= lo && p[3] < hi) col[p[3]] = s[3];
    }
}

// P1[i] = x[i] * dinv[row]; tail block zeroes row N of P1 and P2 (dummy target).
__global__ void prescale_kernel(const float* __restrict__ x, const float* __restrict__ dinv,
                                float* __restrict__ P1, float* __restrict__ P2, int nq) {
    int i = blockIdx.x * blockDim.x + threadIdx.x;
    if (i < nq) {
        float d = dinv[i >> 4];
        float4 v = ((const float4*)x)[i];
        ((float4*)P1)[i] = make_float4(v.x * d, v.y * d, v.z * d, v.w * d);
    } else if (i < nq + 16) {
        const float4 z = make_float4(0.f, 0.f, 0.f, 0.f);
        ((float4*)P1)[i] = z;   // row N of P1  (P1 has N+1 rows; i in [nq,nq+16))
        ((float4*)P2)[i] = z;   // row N of P2
    }
}

// ---------- fused layer: gather-sum -> LDS -> GEMM -> bias/act ----------
// 16 nodes/block, 16 lanes/node (float4/lane). Lists padded to x8: branch-free
// 8-wide loop, col read as 2x int4, 8 float4 gathers in flight, 4 independent
// accumulators. Dummy entries hit zeroed row N. Input pre-scaled by dinv[src].
template<int INTER>
__global__ __launch_bounds__(256) void layer_kernel(
    const int* __restrict__ rowptr, const int* __restrict__ col,
    const float* __restrict__ dinv, const float* __restrict__ Xs,
    const float* __restrict__ W, const float* __restrict__ bias,
    float* __restrict__ out, int n) {
    __shared__ float w_lds[FEAT * FEAT];   // [k][c]
    __shared__ float s_tile[16 * STILE];   // [r][k], padded

    const int t = threadIdx.x;
#pragma unroll
    for (int i = 0; i < 4; ++i) {
        int idx = (i * 256 + t) * 4;
        *(float4*)&w_lds[idx] = *(const float4*)&W[idx];
    }
    __syncthreads();   // W visible; nothing else needs a barrier below

    const int r  = t >> 4;       // local node 0..15
    const int c4 = t & 15;       // float4 feature group
    const int g  = blockIdx.x * 16 + r;
    if (g >= n) return;
    const int f = c4 * 4;
    const float* __restrict__ Hf = Xs + f;

    // self-loop term (input pre-scaled)
    float4 a0 = *(const float4*)&Hf[(size_t)g * FEAT];
    float4 a1 = make_float4(0.f, 0.f, 0.f, 0.f);
    float4 a2 = make_float4(0.f, 0.f, 0.f, 0.f);
    float4 a3 = make_float4(0.f, 0.f, 0.f, 0.f);

    int p = rowptr[g];
    const int end = rowptr[g + 1];   // end - p is a multiple of 8

    for (; p < end; p += 8) {
        const v4i c0 = *(const v4i*)&col[p];
        const v4i c1 = *(const v4i*)&col[p + 4];
        const float4 h0 = *(const float4*)&Hf[(size_t)c0[0] * FEAT];
        const float4 h1 = *(const float4*)&Hf[(size_t)c0[1] * FEAT];
        const float4 h2 = *(const float4*)&Hf[(size_t)c0[2] * FEAT];
        const float4 h3 = *(const float4*)&Hf[(size_t)c0[3] * FEAT];
        const float4 h4 = *(const float4*)&Hf[(size_t)c1[0] * FEAT];
        const float4 h5 = *(const float4*)&Hf[(size_t)c1[1] * FEAT];
        const float4 h6 = *(const float4*)&Hf[(size_t)c1[2] * FEAT];
        const float4 h7 = *(const float4*)&Hf[(size_t)c1[3] * FEAT];
        a0.x += h0.x; a0.y += h0.y; a0.z += h0.z; a0.w += h0.w;
        a1.x += h1.x; a1.y += h1.y; a1.z += h1.z; a1.w += h1.w;
        a2.x += h2.x; a2.y += h2.y; a2.z += h2.z; a2.w += h2.w;
        a3.x += h3.x; a3.y += h3.y; a3.z += h3.z; a3.w += h3.w;
        a0.x += h4.x; a0.y += h4.y; a0.z += h4.z; a0.w += h4.w;
        a1.x += h5.x; a1.y += h5.y; a1.z += h5.z; a1.w += h5.w;
        a2.x += h6.x; a2.y += h6.y; a2.z += h6.z; a2.w += h6.w;
        a3.x += h7.x; a3.y += h7.y; a3.z += h7.z; a3.w += h7.w;
    }
    float4 S = make_float4((a0.x + a1.x) + (a2.x + a3.x),
                           (a0.y + a1.y) + (a2.y + a3.y),
                           (a0.z + a1.z) + (a2.z + a3.z),
                           (a0.w + a1.w) + (a2.w + a3.w));
    *(float4*)&s_tile[r * STILE + f] = S;
    // no __syncthreads: wave w reads only rows 4w..4w+3, which it wrote

    // in-block GEMM: T[r][f..f+3] = sum_k S[r][k] * W[k][f..f+3]
    float4 acc = make_float4(0.f, 0.f, 0.f, 0.f);
#pragma unroll
    for (int k = 0; k < FEAT; ++k) {
        const float sv = s_tile[r * STILE + k];
        const float4 wv = *(const float4*)&w_lds[k * FEAT + f];
        acc.x += sv * wv.x; acc.y += sv * wv.y;
        acc.z += sv * wv.z; acc.w += sv * wv.w;
    }

    const float dg = dinv[g];
    const float4 bv = *(const float4*)&bias[f];
    float4 o = make_float4(acc.x * dg + bv.x, acc.y * dg + bv.y,
                           acc.z * dg + bv.z, acc.w * dg + bv.w);
    if (INTER) {   // ReLU, then pre-scale for next layer's gather
        o.x = fmaxf(o.x, 0.f) * dg; o.y = fmaxf(o.y, 0.f) * dg;
        o.z = fmaxf(o.z, 0.f) * dg; o.w = fmaxf(o.w, 0.f) * dg;
    }
    *(float4*)&out[(size_t)g * FEAT + f] = o;
}

extern "C" void kernel_launch(void* const* d_in, const int* in_sizes, int n_in,
                              void* d_out, int out_size, void* d_ws, size_t ws_size,
                              hipStream_t stream) {
    const float* x  = (const float*)d_in[0];
    const int*   ei = (const int*)d_in[1];
    const float* W0 = (const float*)d_in[2];
    const float* b0 = (const float*)d_in[3];
    const float* W1 = (const float*)d_in[4];
    const float* b1 = (const float*)d_in[5];
    const float* W2 = (const float*)d_in[6];
    const float* b2 = (const float*)d_in[7];
    float* out = (float*)d_out;

    const int N = in_sizes[0] / FEAT;   // 50000
    const int E = in_sizes[1] / 2;      // 800000 (divisible by 4)
    const int* src = ei;
    const int* dst = ei + E;

    const int nbScan = (N + SCAN_B - 1) / SCAN_B;   // 49 (<= 64 for scan_finish)
    const int Ecap = E + 8 * N;                      // padded col capacity

    // workspace layout (64B-aligned regions)
    char* w = (char*)d_ws;
    auto take = [&](size_t bytes) { char* p = w; w += (bytes + 63) & ~(size_t)63; return p; };
    int*   cnt    = (int*)take(sizeof(int) * (size_t)N);
    int*   rowptr = (int*)take(sizeof(int) * (size_t)(N + 1));
    int*   bsum   = (int*)take(sizeof(int) * (size_t)(nbScan + 1));
    int*   col    = (int*)take(sizeof(int) * (size_t)Ecap);
    float* dinv   = (float*)take(sizeof(float) * (size_t)N);
    float* P1     = (float*)take(sizeof(float) * ((size_t)(N + 1) * FEAT));
    float* P2     = (float*)take(sizeof(float) * ((size_t)(N + 1) * FEAT));
    int*   rank = (int*)P2;   // alias: dead before layer-0 gemm writes P2
    int*   pos  = (int*)P1;   // alias: dead before prescale writes P1

    const int tB = 256;
    const int E4  = E / 4;
    const int gE4 = (E4 + tB - 1) / tB;
    const int g16 = (N + 15) / 16;
    const int qn  = (N + 7) / 8;        // nodes per scatter partition
    const int nq  = N * FEAT / 4;
    const int gQ  = (nq + 16 + tB - 1) / tB;   // +16 float4s for row-N zeroing

    // CSR build (shared by all 3 layers)
    hipMemsetAsync(cnt, 0, sizeof(int) * (size_t)N, stream);
    deg_rank_kernel<<<gE4, tB, 0, stream>>>(dst, cnt, rank, E4);
    scan_partial_kernel<<<nbScan, SCAN_B, 0, stream>>>(cnt, rowptr, bsum, dinv, N);
    scan_finish_kernel<<<nbScan, SCAN_B, 0, stream>>>(cnt, rowptr, bsum, col, N, nbScan, N);
    pos_kernel<<<gE4, tB, 0, stream>>>(dst, rank, rowptr, pos, E4);
    scatter_kernel<<<gE4 * 8, tB, 0, stream>>>(pos, src, rowptr, col, E4, qn, N);

    // prescale input into P1 (pos already consumed); zero row N of P1/P2
    prescale_kernel<<<gQ, tB, 0, stream>>>(x, dinv, P1, P2, nq);

    // fused layers
    layer_kernel<1><<<g16, tB, 0, stream>>>(rowptr, col, dinv, P1, W0, b0, P2, N);
    layer_kernel<1><<<g16, tB, 0, stream>>>(rowptr, col, dinv, P2, W1, b1, P1, N);
    layer_kernel<0><<<g16, tB, 0, stream>>>(rowptr, col, dinv, P1, W2, b2, out, N);
}

// Round 13
// 232.807 us; speedup vs baseline: 1.8551x; 1.0082x over previous
//
#include <hip/hip_runtime.h>

// GCN 3-layer forward, fp32 — Round 13: pos folded into scatter (9 dispatches).
//   Layers (proven, R11): gather-sum (node-parallel float4, 8-wide branch-free
//   over x8-padded lists, dummy=N -> zeroed row N) -> LDS GEMM -> epilogue.
//   Build: memset(cnt) -> deg_rank -> scan_partial -> scan_finish (bsum scan +
//   offset add + pad fill) -> scatter (8x dst-range partitioned, pos computed
//   inline) -> prescale (fused row-N zeroing).

#define FEAT 64
#define SCAN_B 1024
#define STILE 68   // s_tile stride: breaks 4-way LDS bank conflict on k-loop

typedef int v4i __attribute__((ext_vector_type(4)));

// ---------- CSR build ----------
// degree count; atomic return value = within-row rank of edge e.
__global__ void deg_rank_kernel(const int* __restrict__ dst, int* __restrict__ cnt,
                                int* __restrict__ rank, int E4) {
    int i = blockIdx.x * blockDim.x + threadIdx.x;
    if (i < E4) {
        v4i d = __builtin_nontemporal_load(((const v4i*)dst) + i);
        v4i r;
        r[0] = atomicAdd(&cnt[d[0]], 1);
        r[1] = atomicAdd(&cnt[d[1]], 1);
        r[2] = atomicAdd(&cnt[d[2]], 1);
        r[3] = atomicAdd(&cnt[d[3]], 1);
        __builtin_nontemporal_store(r, ((v4i*)rank) + i);
    }
}

// Pass 1: exclusive scan over counts PADDED to multiple of 8 -> rowptr
// (chunk-local), bsum. dinv from RAW count: rsqrt(1+cnt).
__global__ __launch_bounds__(SCAN_B) void scan_partial_kernel(
    const int* __restrict__ cnt, int* __restrict__ rowptr,
    int* __restrict__ bsum, float* __restrict__ dinv, int n) {
    __shared__ int wsum[SCAN_B / 64 + 1];
    const int tid  = threadIdx.x;
    const int lane = tid & 63;
    const int wid  = tid >> 6;
    const int i = blockIdx.x * SCAN_B + tid;

    int vr = (i < n) ? cnt[i] : 0;
    if (i < n) dinv[i] = rsqrtf((float)(1 + vr));
    int v = (vr + 7) & ~7;            // pad each list to multiple of 8
    int incl = v;
#pragma unroll
    for (int off = 1; off < 64; off <<= 1) {
        int t = __shfl_up(incl, off, 64);
        if (lane >= off) incl += t;
    }
    if (lane == 63) wsum[wid] = incl;
    __syncthreads();
    if (tid == 0) {
        int run = 0;
#pragma unroll
        for (int w = 0; w < SCAN_B / 64; ++w) { int t = wsum[w]; wsum[w] = run; run += t; }
        wsum[SCAN_B / 64] = run;
        bsum[blockIdx.x] = run;
    }
    __syncthreads();
    if (i < n) rowptr[i] = incl - v + wsum[wid];
}

// Pass 2 (fused): every block wave-scans bsum (nb<=64) to get its own offset,
// adds it, writes rowptr[n], and fills each list's padding slots with dummy.
__global__ __launch_bounds__(SCAN_B) void scan_finish_kernel(
    const int* __restrict__ cnt, int* __restrict__ rowptr,
    const int* __restrict__ bsum, int* __restrict__ col,
    int n, int nb, int dummy) {
    __shared__ int s_off, s_tot;
    const int tid = threadIdx.x;
    if (tid < 64) {
        int v = (tid < nb) ? bsum[tid] : 0;
        int incl = v;
#pragma unroll
        for (int off = 1; off < 64; off <<= 1) {
            int t = __shfl_up(incl, off, 64);
            if ((tid & 63) >= off) incl += t;
        }
        if (tid == (int)blockIdx.x) s_off = incl - v;  // exclusive offset
        if (tid == 63) s_tot = incl;                   // grand total
    }
    __syncthreads();
    const int i = blockIdx.x * SCAN_B + tid;
    if (i < n) {
        const int rp = rowptr[i] + s_off;
        rowptr[i] = rp;
        const int c = cnt[i];
        const int e = rp + ((c + 7) & ~7);
        for (int p = rp + c; p < e; ++p) col[p] = dummy;
    }
    if (i == 0) rowptr[n] = s_tot;
}

// dst-range-partitioned scatter with inline pos: q = blockIdx&7 owns dst nodes
// [q*qn, (q+1)*qn) -> a contiguous col region; only q's XCD dirties those
// lines (full-line writebacks). rowptr gather is L2-resident (200 KB).
__global__ void scatter_kernel(const int* __restrict__ src, const int* __restrict__ dst,
                               const int* __restrict__ rank, const int* __restrict__ rowptr,
                               int* __restrict__ col, int E4, int qn, int n) {
    const int q = blockIdx.x & 7;
    const int i = (blockIdx.x >> 3) * blockDim.x + threadIdx.x;
    const int nlo = q * qn;
    const int nhi = (nlo + qn < n) ? nlo + qn : n;
    if (i < E4) {
        v4i s = __builtin_nontemporal_load(((const v4i*)src) + i);
        v4i d = __builtin_nontemporal_load(((const v4i*)dst) + i);
        v4i r = __builtin_nontemporal_load(((const v4i*)rank) + i);
#pragma unroll
        for (int j = 0; j < 4; ++j) {
            if (d[j] >= nlo && d[j] < nhi) col[rowptr[d[j]] + r[j]] = s[j];
        }
    }
}

// P1[i] = x[i] * dinv[row]; tail block zeroes row N of P1 and P2 (dummy target).
__global__ void prescale_kernel(const float* __restrict__ x, const float* __restrict__ dinv,
                                float* __restrict__ P1, float* __restrict__ P2, int nq) {
    int i = blockIdx.x * blockDim.x + threadIdx.x;
    if (i < nq) {
        float d = dinv[i >> 4];
        float4 v = ((const float4*)x)[i];
        ((float4*)P1)[i] = make_float4(v.x * d, v.y * d, v.z * d, v.w * d);
    } else if (i < nq + 16) {
        const float4 z = make_float4(0.f, 0.f, 0.f, 0.f);
        ((float4*)P1)[i] = z;   // row N of P1
        ((float4*)P2)[i] = z;   // row N of P2
    }
}

// ---------- fused layer: gather-sum -> LDS -> GEMM -> bias/act ----------
// 16 nodes/block, 16 lanes/node (float4/lane). Lists padded to x8: branch-free
// 8-wide loop, col read as 2x int4, 8 float4 gathers in flight, 4 independent
// accumulators. Dummy entries hit zeroed row N. Input pre-scaled by dinv[src].
template<int INTER>
__global__ __launch_bounds__(256) void layer_kernel(
    const int* __restrict__ rowptr, const int* __restrict__ col,
    const float* __restrict__ dinv, const float* __restrict__ Xs,
    const float* __restrict__ W, const float* __restrict__ bias,
    float* __restrict__ out, int n) {
    __shared__ float w_lds[FEAT * FEAT];   // [k][c]
    __shared__ float s_tile[16 * STILE];   // [r][k], padded

    const int t = threadIdx.x;
#pragma unroll
    for (int i = 0; i < 4; ++i) {
        int idx = (i * 256 + t) * 4;
        *(float4*)&w_lds[idx] = *(const float4*)&W[idx];
    }
    __syncthreads();   // W visible; nothing else needs a barrier below

    const int r  = t >> 4;       // local node 0..15
    const int c4 = t & 15;       // float4 feature group
    const int g  = blockIdx.x * 16 + r;
    if (g >= n) return;
    const int f = c4 * 4;
    const float* __restrict__ Hf = Xs + f;

    // self-loop term (input pre-scaled)
    float4 a0 = *(const float4*)&Hf[(size_t)g * FEAT];
    float4 a1 = make_float4(0.f, 0.f, 0.f, 0.f);
    float4 a2 = make_float4(0.f, 0.f, 0.f, 0.f);
    float4 a3 = make_float4(0.f, 0.f, 0.f, 0.f);

    int p = rowptr[g];
    const int end = rowptr[g + 1];   // end - p is a multiple of 8

    for (; p < end; p += 8) {
        const v4i c0 = *(const v4i*)&col[p];
        const v4i c1 = *(const v4i*)&col[p + 4];
        const float4 h0 = *(const float4*)&Hf[(size_t)c0[0] * FEAT];
        const float4 h1 = *(const float4*)&Hf[(size_t)c0[1] * FEAT];
        const float4 h2 = *(const float4*)&Hf[(size_t)c0[2] * FEAT];
        const float4 h3 = *(const float4*)&Hf[(size_t)c0[3] * FEAT];
        const float4 h4 = *(const float4*)&Hf[(size_t)c1[0] * FEAT];
        const float4 h5 = *(const float4*)&Hf[(size_t)c1[1] * FEAT];
        const float4 h6 = *(const float4*)&Hf[(size_t)c1[2] * FEAT];
        const float4 h7 = *(const float4*)&Hf[(size_t)c1[3] * FEAT];
        a0.x += h0.x; a0.y += h0.y; a0.z += h0.z; a0.w += h0.w;
        a1.x += h1.x; a1.y += h1.y; a1.z += h1.z; a1.w += h1.w;
        a2.x += h2.x; a2.y += h2.y; a2.z += h2.z; a2.w += h2.w;
        a3.x += h3.x; a3.y += h3.y; a3.z += h3.z; a3.w += h3.w;
        a0.x += h4.x; a0.y += h4.y; a0.z += h4.z; a0.w += h4.w;
        a1.x += h5.x; a1.y += h5.y; a1.z += h5.z; a1.w += h5.w;
        a2.x += h6.x; a2.y += h6.y; a2.z += h6.z; a2.w += h6.w;
        a3.x += h7.x; a3.y += h7.y; a3.z += h7.z; a3.w += h7.w;
    }
    float4 S = make_float4((a0.x + a1.x) + (a2.x + a3.x),
                           (a0.y + a1.y) + (a2.y + a3.y),
                           (a0.z + a1.z) + (a2.z + a3.z),
                           (a0.w + a1.w) + (a2.w + a3.w));
    *(float4*)&s_tile[r * STILE + f] = S;
    // no __syncthreads: wave w reads only rows 4w..4w+3, which it wrote

    // in-block GEMM: T[r][f..f+3] = sum_k S[r][k] * W[k][f..f+3]
    float4 acc = make_float4(0.f, 0.f, 0.f, 0.f);
#pragma unroll
    for (int k = 0; k < FEAT; ++k) {
        const float sv = s_tile[r * STILE + k];
        const float4 wv = *(const float4*)&w_lds[k * FEAT + f];
        acc.x += sv * wv.x; acc.y += sv * wv.y;
        acc.z += sv * wv.z; acc.w += sv * wv.w;
    }

    const float dg = dinv[g];
    const float4 bv = *(const float4*)&bias[f];
    float4 o = make_float4(acc.x * dg + bv.x, acc.y * dg + bv.y,
                           acc.z * dg + bv.z, acc.w * dg + bv.w);
    if (INTER) {   // ReLU, then pre-scale for next layer's gather
        o.x = fmaxf(o.x, 0.f) * dg; o.y = fmaxf(o.y, 0.f) * dg;
        o.z = fmaxf(o.z, 0.f) * dg; o.w = fmaxf(o.w, 0.f) * dg;
    }
    *(float4*)&out[(size_t)g * FEAT + f] = o;
}

extern "C" void kernel_launch(void* const* d_in, const int* in_sizes, int n_in,
                              void* d_out, int out_size, void* d_ws, size_t ws_size,
                              hipStream_t stream) {
    const float* x  = (const float*)d_in[0];
    const int*   ei = (const int*)d_in[1];
    const float* W0 = (const float*)d_in[2];
    const float* b0 = (const float*)d_in[3];
    const float* W1 = (const float*)d_in[4];
    const float* b1 = (const float*)d_in[5];
    const float* W2 = (const float*)d_in[6];
    const float* b2 = (const float*)d_in[7];
    float* out = (float*)d_out;

    const int N = in_sizes[0] / FEAT;   // 50000
    const int E = in_sizes[1] / 2;      // 800000 (divisible by 4)
    const int* src = ei;
    const int* dst = ei + E;

    const int nbScan = (N + SCAN_B - 1) / SCAN_B;   // 49 (<= 64 for scan_finish)
    const int Ecap = E + 8 * N;                      // padded col capacity

    // workspace layout (64B-aligned regions)
    char* w = (char*)d_ws;
    auto take = [&](size_t bytes) { char* p = w; w += (bytes + 63) & ~(size_t)63; return p; };
    int*   cnt    = (int*)take(sizeof(int) * (size_t)N);
    int*   rowptr = (int*)take(sizeof(int) * (size_t)(N + 1));
    int*   bsum   = (int*)take(sizeof(int) * (size_t)(nbScan + 1));
    int*   col    = (int*)take(sizeof(int) * (size_t)Ecap);
    float* dinv   = (float*)take(sizeof(float) * (size_t)N);
    float* P1     = (float*)take(sizeof(float) * ((size_t)(N + 1) * FEAT));
    float* P2     = (float*)take(sizeof(float) * ((size_t)(N + 1) * FEAT));
    int*   rank = (int*)P2;   // alias: rank dead before layer-0 gemm writes P2

    const int tB = 256;
    const int E4  = E / 4;
    const int gE4 = (E4 + tB - 1) / tB;
    const int g16 = (N + 15) / 16;
    const int qn  = (N + 7) / 8;        // nodes per scatter partition
    const int nq  = N * FEAT / 4;
    const int gQ  = (nq + 16 + tB - 1) / tB;   // +16 float4s for row-N zeroing

    // CSR build (shared by all 3 layers)
    hipMemsetAsync(cnt, 0, sizeof(int) * (size_t)N, stream);
    deg_rank_kernel<<<gE4, tB, 0, stream>>>(dst, cnt, rank, E4);
    scan_partial_kernel<<<nbScan, SCAN_B, 0, stream>>>(cnt, rowptr, bsum, dinv, N);
    scan_finish_kernel<<<nbScan, SCAN_B, 0, stream>>>(cnt, rowptr, bsum, col, N, nbScan, N);
    scatter_kernel<<<gE4 * 8, tB, 0, stream>>>(src, dst, rank, rowptr, col, E4, qn, N);

    // prescale input into P1; zero row N of P1/P2 (dummy gather target)
    prescale_kernel<<<gQ, tB, 0, stream>>>(x, dinv, P1, P2, nq);

    // fused layers
    layer_kernel<1><<<g16, tB, 0, stream>>>(rowptr, col, dinv, P1, W0, b0, P2, N);
    layer_kernel<1><<<g16, tB, 0, stream>>>(rowptr, col, dinv, P2, W1, b1, P1, N);
    layer_kernel<0><<<g16, tB, 0, stream>>>(rowptr, col, dinv, P1, W2, b2, out, N);
}